// Round 9
// baseline (584.826 us; speedup 1.0000x reference)
//
#include <hip/hip_runtime.h>

#define NBINS 256
#define NCHAN 192                 // 64*3 channels
#define BPC 8                     // sibling blocks per channel
#define TPB 256                   // 4 waves/block; grid 1536 = EXACTLY 6 blocks/CU
#define PPT 32                    // packed u32 per thread (128 px) held in VGPRs
#define NCOPY 16                  // replicated LDS copies: lanes 4k..4k+3 -> copy k (~2-way, free m136)
#define F4_PER_BLK (TPB * PPT)    // 8192 float4 per block strip

typedef float f4 __attribute__((ext_vector_type(4)));

// Register-retention fused equalize (deletes the 100 MB packed round-trip):
// issued bytes = 201(x) + 201(out) + ~3 MB partials -> 64 us floor on the
// validated per-CU issue model (time ~= issued bytes / 10.2 B/cyc/CU).
//
// DEADLOCK SAFETY (manual capacity arithmetic, declared via __launch_bounds__):
// grid 1536 = 256 CUs x 6 blocks; residency per CU: waves 24/32, LDS
// 6x17.4=105/160 KiB, VGPR capped at 84 by __launch_bounds__(256,6) (spills
// rather than dropping occupancy). Grid <= capacity => all blocks resident
// from t=0 => the channel-local flag wait (8 siblings) always satisfies.
// Cross-XCD visibility per G16: release fence + agent-scope atomics.
__global__ __launch_bounds__(TPB, 6) void eq_fused(const float* __restrict__ x,
                                                   float* __restrict__ out,
                                                   int* __restrict__ partials,
                                                   int* __restrict__ done) {
    __shared__ int lh[NBINS * NCOPY];   // 16 KiB; reused as float LUT in phase C
    __shared__ int scan[NBINS];
    __shared__ int s_last_idx, s_last;

    const int bid  = blockIdx.x;
    const int chan = bid / BPC;
    const int tid  = threadIdx.x;
    const int cp   = (tid & 63) >> 2;

    for (int i = tid; i < NBINS * NCOPY; i += TPB) lh[i] = 0;
    if (tid == 0) s_last_idx = 0;
    __syncthreads();

    // ---- Phase A: read strip once (nt), clamp->u8, retain in VGPRs, histogram ----
    const size_t base = (size_t)bid * F4_PER_BLK;
    const f4* bx = (const f4*)x + base;

    unsigned px[PPT];                   // fully-static indexing (rule #20)
    #pragma unroll
    for (int k = 0; k < PPT; ++k) {
        f4 v = __builtin_nontemporal_load(&bx[tid + k * TPB]);
        int a = (int)fminf(fmaxf(v.x, 0.f), 255.f);
        int b = (int)fminf(fmaxf(v.y, 0.f), 255.f);
        int c = (int)fminf(fmaxf(v.z, 0.f), 255.f);
        int d = (int)fminf(fmaxf(v.w, 0.f), 255.f);
        px[k] = (unsigned)(a | (b << 8) | (c << 16) | (d << 24));
        atomicAdd(&lh[(a << 4) + cp], 1);
        atomicAdd(&lh[(b << 4) + cp], 1);
        atomicAdd(&lh[(c << 4) + cp], 1);
        atomicAdd(&lh[(d << 4) + cp], 1);
    }
    __syncthreads();

    // ---- publish partial: plain stores -> release fence -> count ----
    int s = 0;                          // TPB==NBINS: thread owns bin `tid`
    #pragma unroll
    for (int k = 0; k < NCOPY; ++k) s += lh[(tid << 4) + ((tid + k) & 15)];
    partials[bid * NBINS + tid] = s;
    __threadfence();                    // agent-scope release of the partial row
    __syncthreads();
    if (tid == 0)
        __hip_atomic_fetch_add(&done[chan], 1, __ATOMIC_RELEASE, __HIP_MEMORY_SCOPE_AGENT);

    // ---- channel-local wait (8 siblings; all co-resident => bounded) ----
    if (tid == 0) {
        while (__hip_atomic_load(&done[chan], __ATOMIC_ACQUIRE, __HIP_MEMORY_SCOPE_AGENT) < BPC)
            __builtin_amdgcn_s_sleep(8);
    }
    __syncthreads();

    // ---- Phase B: sum 8 partials (agent-scope loads bypass stale L1), scan, LUT ----
    int h = 0;
    #pragma unroll
    for (int b = 0; b < BPC; ++b)
        h += __hip_atomic_load(&partials[(chan * BPC + b) * NBINS + tid],
                               __ATOMIC_RELAXED, __HIP_MEMORY_SCOPE_AGENT);
    scan[tid] = h;
    __syncthreads();                    // also: last lh use before slut reuse
    if (h > 0) atomicMax(&s_last_idx, tid);

    for (int off = 1; off < NBINS; off <<= 1) {    // inclusive Hillis-Steele
        int t = (tid >= off) ? scan[tid - off] : 0;
        __syncthreads();
        scan[tid] += t;
        __syncthreads();
    }
    if (tid == s_last_idx) s_last = h;  // count of last nonzero bin
    __syncthreads();

    const int total = scan[NBINS - 1];
    const int step  = (total - s_last) / 255;      // floor, nonneg; exact-int
                                                   // (all intermediates < 2^24)
    float lutv;
    if (step == 0)      lutv = (float)tid;         // identity
    else if (tid == 0)  lutv = 0.f;                // shifted-in leading zero
    else {
        int l = (scan[tid - 1] + (step >> 1)) / step;
        lutv = (float)(l < 255 ? l : 255);
    }
    float* slut = (float*)lh;
    #pragma unroll
    for (int k = 0; k < NCOPY; ++k) slut[(tid << 4) + ((tid + k) & 15)] = lutv;
    __syncthreads();

    // ---- Phase C: apply from registers, nontemporal store ----
    f4* bo = (f4*)out + base;
    #pragma unroll
    for (int k = 0; k < PPT; ++k) {
        unsigned p = px[k];
        f4 o;
        o.x = slut[(int)((p & 255u) << 4) + cp];
        o.y = slut[(int)(((p >> 8) & 255u) << 4) + cp];
        o.z = slut[(int)(((p >> 16) & 255u) << 4) + cp];
        o.w = slut[(int)((p >> 24) << 4) + cp];
        __builtin_nontemporal_store(o, &bo[tid + k * TPB]);
    }
}

// ws is poisoned each iteration: zero the 192 channel flags first (raceless,
// ordered by the stream before eq_fused).
__global__ void eq_zero_flags(int* __restrict__ done) {
    if (threadIdx.x < NCHAN) done[threadIdx.x] = 0;
}

extern "C" void kernel_launch(void* const* d_in, const int* in_sizes, int n_in,
                              void* d_out, int out_size, void* d_ws, size_t ws_size,
                              hipStream_t stream) {
    const float* x = (const float*)d_in[0];
    // d_in[1] is `magnitude` — unused by the reference.
    float* out = (float*)d_out;

    // ws layout: [partials: 1536*256 ints = 1.5 MiB][done flags: 192 ints]
    int* partials = (int*)d_ws;
    int* done = partials + (size_t)NCHAN * BPC * NBINS;

    eq_zero_flags<<<1, TPB, 0, stream>>>(done);
    eq_fused<<<NCHAN * BPC, TPB, 0, stream>>>(x, out, partials, done);
}